// Round 1
// baseline (1240.692 us; speedup 1.0000x reference)
//
#include <hip/hip_runtime.h>
#include <float.h>

#define NQ      4096
#define NKEYS   65536
#define DKDIM   128
#define DVDIM   128
#define TOPK_N  32
#define NSPLIT  8
#define KPS     (NKEYS / NSPLIT)        // 8192 keys per split
#define BQ      64                      // queries per block (4 waves x 16)
#define NCAND   (NSPLIT * TOPK_N)       // 256 candidates per query
#define NOUT    ((size_t)NQ * TOPK_N * DKDIM)

typedef __attribute__((ext_vector_type(8))) short short8;   // 8 bf16
typedef __attribute__((ext_vector_type(4))) float v4f;      // MFMA acc

__device__ inline unsigned short f2bf(float f) {            // RNE fp32->bf16
    unsigned int u = __float_as_uint(f);
    return (unsigned short)((u + 0x7FFFu + ((u >> 16) & 1u)) >> 16);
}

// ---------------------------------------------------------------------------
// Kernel A: convert q and keys to bf16 (workspace).
// ---------------------------------------------------------------------------
__global__ __launch_bounds__(256) void convert_kernel(
    const float* __restrict__ q, const float* __restrict__ keys,
    unsigned short* __restrict__ qbf, unsigned short* __restrict__ kbf)
{
    const size_t QG = (size_t)NQ * DKDIM / 8;       // 65536 groups of 8
    const size_t KG = (size_t)NKEYS * DKDIM / 8;    // 1048576
    const size_t g  = (size_t)blockIdx.x * 256 + threadIdx.x;
    if (g >= QG + KG) return;
    const float* src;
    unsigned short* dst;
    if (g < QG) { src = q + g * 8;         dst = qbf + g * 8; }
    else        { const size_t h = g - QG; src = keys + h * 8; dst = kbf + h * 8; }
    const float4 a = ((const float4*)src)[0];
    const float4 b = ((const float4*)src)[1];
    short8 o;
    o[0] = (short)f2bf(a.x); o[1] = (short)f2bf(a.y);
    o[2] = (short)f2bf(a.z); o[3] = (short)f2bf(a.w);
    o[4] = (short)f2bf(b.x); o[5] = (short)f2bf(b.y);
    o[6] = (short)f2bf(b.z); o[7] = (short)f2bf(b.w);
    *(short8*)dst = o;
}

// ---------------------------------------------------------------------------
// Kernel B: bf16 MFMA approx scores + per-(query,split) approx-top-32 pools.
// Grid (NQ/BQ, NSPLIT). Block 256 = 4 waves; wave w owns queries
// [blockIdx.x*64 + 16w, +16) and scans all 8192 split keys, 16 per iter.
// MFMA 16x16x32: A = Q-tile (lane: Q[q0+(l&15)][ (l>>4)*8+j + 32t ]),
//                B = K-tile (lane: K[n0+(l&15)][ same d ]),
//                D: lane l, reg r -> S[q0 + (l>>4)*4 + r][n0 + (l&15)].
// Selection: per 16-lane quad (owns queries q0+quad*4+r), ballot-filtered
// replace-min pools in LDS, argmin via intra-quad butterfly.
// ---------------------------------------------------------------------------
__global__ __launch_bounds__(256) void score_select_kernel(
    const unsigned short* __restrict__ qbf, const unsigned short* __restrict__ kbf,
    int* __restrict__ cand)
{
    __shared__ float pv[BQ][TOPK_N];    // 8 KB, wave-private rows
    __shared__ int   pix[BQ][TOPK_N];   // 8 KB

    const int tid  = threadIdx.x;
    const int wave = tid >> 6;
    const int lane = tid & 63;
    const int l16  = lane & 15;
    const int quad = lane >> 4;
    const int q0   = blockIdx.x * BQ + wave * 16;
    const int nbase = blockIdx.y * KPS;

    for (int i = tid; i < BQ * TOPK_N; i += 256) {
        pv[i >> 5][i & 31]  = -FLT_MAX;
        pix[i >> 5][i & 31] = 0;
    }
    __syncthreads();

    // A fragments (q-tile), resident for the whole kernel.
    short8 afrag[4];
#pragma unroll
    for (int t = 0; t < 4; ++t)
        afrag[t] = *(const short8*)(qbf + (size_t)(q0 + l16) * DKDIM + t * 32 + quad * 8);

    // Cached pool min/argmin for this lane's quad queries (q0 + quad*4 + r).
    float vm[4]; int pp[4];
#pragma unroll
    for (int r = 0; r < 4; ++r) { vm[r] = -FLT_MAX; pp[r] = 0; }

    for (int it = 0; it < KPS / 16; ++it) {
        const int n0 = nbase + it * 16;
        const unsigned short* kb = kbf + (size_t)(n0 + l16) * DKDIM + quad * 8;
        v4f acc = {0.f, 0.f, 0.f, 0.f};
#pragma unroll
        for (int t = 0; t < 4; ++t) {
            const short8 bfrag = *(const short8*)(kb + t * 32);
            acc = __builtin_amdgcn_mfma_f32_16x16x32_bf16(afrag[t], bfrag, acc, 0, 0, 0);
        }
#pragma unroll
        for (int r = 0; r < 4; ++r) {
            unsigned long long m = __ballot(acc[r] > vm[r]);
            while (m) {   // m wave-uniform
                // One hit per quad per round; clear mask computed uniformly.
                unsigned long long clearm = 0;
#pragma unroll
                for (int p = 0; p < 4; ++p) {
                    const unsigned int mp = (unsigned int)(m >> (p * 16)) & 0xFFFFu;
                    if (mp) clearm |= 1ULL << (p * 16 + __builtin_ctz(mp));
                }
                const unsigned int mq = (unsigned int)(m >> (quad * 16)) & 0xFFFFu;
                const bool has = (mq != 0);
                const int  src = has ? (quad * 16 + __builtin_ctz(mq)) : lane;
                const float v  = __shfl(acc[r], src);   // per-lane src (bpermute)
                if (has && v > vm[r]) {   // uniform within each quad
                    const int qq = wave * 16 + quad * 4 + r;
                    if (l16 == 0) { pv[qq][pp[r]] = v; pix[qq][pp[r]] = n0 + (src & 15); }
                    // Recompute pool argmin: 16 lanes x 2 slots + 4-step butterfly.
                    float s0 = pv[qq][l16];
                    int   p0 = l16;
                    const float s1 = pv[qq][l16 + 16];
                    if (s1 < s0) { s0 = s1; p0 = l16 + 16; }
#pragma unroll
                    for (int off = 1; off < 16; off <<= 1) {
                        const float os = __shfl_xor(s0, off);
                        const int   op = __shfl_xor(p0, off);
                        if (os < s0) { s0 = os; p0 = op; }
                    }
                    vm[r] = s0; pp[r] = p0;
                }
                m &= ~clearm;
            }
        }
    }

    // Writeout (pools are wave-private; no barrier needed).
    for (int i = lane; i < 16 * TOPK_N; i += 64) {
        const int qq = i >> 5, ss = i & 31;
        cand[((size_t)(q0 + qq) * NSPLIT + blockIdx.y) * TOPK_N + ss] = pix[wave * 16 + qq][ss];
    }
}

// ---------------------------------------------------------------------------
// Kernel C: exact fp32 rescore of 256 candidates (sequential fmaf chain,
// bitwise-matches reference), bitonic sort (desc, tie -> lower idx), gather.
// One block (256 threads) per query.
// ---------------------------------------------------------------------------
__global__ __launch_bounds__(256) void rescore_gather_kernel(
    const float* __restrict__ qg, const float* __restrict__ keys,
    const float* __restrict__ values, const int* __restrict__ cand,
    float* __restrict__ out)
{
    __shared__ float qrow[DKDIM];
    __shared__ float ss[NCAND];
    __shared__ int   si[NCAND];
    const int bt  = blockIdx.x;
    const int tid = threadIdx.x;

    if (tid < DKDIM) qrow[tid] = qg[(size_t)bt * DKDIM + tid];
    __syncthreads();

    const int idx = cand[(size_t)bt * NCAND + tid];
    const float4* krow = (const float4*)(keys + (size_t)idx * DKDIM);
    float s = 0.f;
#pragma unroll
    for (int d4 = 0; d4 < DKDIM / 4; ++d4) {
        const float4 k4 = krow[d4];
        const float4 q4 = *(const float4*)&qrow[4 * d4];
        s = fmaf(q4.x, k4.x, s);
        s = fmaf(q4.y, k4.y, s);
        s = fmaf(q4.z, k4.z, s);
        s = fmaf(q4.w, k4.w, s);
    }
    ss[tid] = s; si[tid] = idx;
    __syncthreads();

    for (int k = 2; k <= NCAND; k <<= 1) {
        for (int j = k >> 1; j > 0; j >>= 1) {
            const int ixj = tid ^ j;
            if (ixj > tid) {
                const bool dirDesc = ((tid & k) == 0);
                const float sa = ss[tid], sb = ss[ixj];
                const int   ia = si[tid], ib = si[ixj];
                const bool before = (sa > sb) || (sa == sb && ia < ib);
                if (before != dirDesc) {
                    ss[tid] = sb; ss[ixj] = sa;
                    si[tid] = ib; si[ixj] = ia;
                }
            }
            __syncthreads();
        }
    }

    const int lane = tid & 31;
    const int rb   = tid >> 5;
#pragma unroll
    for (int r = 0; r < 4; ++r) {
        const int row = rb + 8 * r;
        const int n   = si[row];
        const float4 kv = *(const float4*)(keys   + (size_t)n * DKDIM + 4 * lane);
        const float4 vv = *(const float4*)(values + (size_t)n * DVDIM + 4 * lane);
        const size_t ob = ((size_t)bt * TOPK_N + row) * DKDIM + 4 * lane;
        *(float4*)(out + ob)        = kv;
        *(float4*)(out + NOUT + ob) = vv;
    }
}

extern "C" void kernel_launch(void* const* d_in, const int* in_sizes, int n_in,
                              void* d_out, int out_size, void* d_ws, size_t ws_size,
                              hipStream_t stream)
{
    const float* q      = (const float*)d_in[0];
    const float* keys   = (const float*)d_in[1];
    const float* values = (const float*)d_in[2];
    float* out = (float*)d_out;

    unsigned short* qbf = (unsigned short*)d_ws;                               // 1 MB
    unsigned short* kbf = (unsigned short*)((char*)d_ws + (1u << 20));         // 16 MB
    int* cand = (int*)((char*)d_ws + (17u << 20));                             // 4 MB

    const int cvt_groups = (NQ + NKEYS) * DKDIM / 8;
    convert_kernel<<<(cvt_groups + 255) / 256, 256, 0, stream>>>(q, keys, qbf, kbf);
    score_select_kernel<<<dim3(NQ / BQ, NSPLIT), 256, 0, stream>>>(qbf, kbf, cand);
    rescore_gather_kernel<<<NQ, 256, 0, stream>>>(q, keys, values, cand, out);
}

// Round 2
// 1156.747 us; speedup vs baseline: 1.0726x; 1.0726x over previous
//
#include <hip/hip_runtime.h>
#include <float.h>

#define NQ      4096
#define NKEYS   65536
#define DKDIM   128
#define DVDIM   128
#define TOPK_N  32
#define NSPLIT  16
#define KPS     (NKEYS / NSPLIT)        // 4096 keys per split
#define BQ      64                      // queries per block (4 waves x 16)
#define NCAND   (NSPLIT * TOPK_N)       // 512 candidates per query
#define NOUT    ((size_t)NQ * TOPK_N * DKDIM)

typedef __attribute__((ext_vector_type(8))) short short8;   // 8 bf16
typedef __attribute__((ext_vector_type(4))) float v4f;      // MFMA acc

__device__ inline unsigned short f2bf(float f) {            // RNE fp32->bf16
    unsigned int u = __float_as_uint(f);
    return (unsigned short)((u + 0x7FFFu + ((u >> 16) & 1u)) >> 16);
}

// ---------------------------------------------------------------------------
// Kernel A: convert q and keys to bf16 (workspace).
// ---------------------------------------------------------------------------
__global__ __launch_bounds__(256) void convert_kernel(
    const float* __restrict__ q, const float* __restrict__ keys,
    unsigned short* __restrict__ qbf, unsigned short* __restrict__ kbf)
{
    const size_t QG = (size_t)NQ * DKDIM / 8;       // 65536 groups of 8
    const size_t KG = (size_t)NKEYS * DKDIM / 8;    // 1048576
    const size_t g  = (size_t)blockIdx.x * 256 + threadIdx.x;
    if (g >= QG + KG) return;
    const float* src;
    unsigned short* dst;
    if (g < QG) { src = q + g * 8;         dst = qbf + g * 8; }
    else        { const size_t h = g - QG; src = keys + h * 8; dst = kbf + h * 8; }
    const float4 a = ((const float4*)src)[0];
    const float4 b = ((const float4*)src)[1];
    short8 o;
    o[0] = (short)f2bf(a.x); o[1] = (short)f2bf(a.y);
    o[2] = (short)f2bf(a.z); o[3] = (short)f2bf(a.w);
    o[4] = (short)f2bf(b.x); o[5] = (short)f2bf(b.y);
    o[6] = (short)f2bf(b.z); o[7] = (short)f2bf(b.w);
    *(short8*)dst = o;
}

// ---------------------------------------------------------------------------
// Kernel B: bf16 MFMA approx scores + per-(query,split) approx-top-32 pools.
// Grid (NQ/BQ, NSPLIT) remapped so each XCD (lin%8) owns 2 splits ->
// kbf slice (2 MB) + qbf (1 MB) stay L2-resident per XCD.
// Block 256 = 4 waves; wave w owns queries [qgrp*64 + 16w, +16) and scans
// all KPS split keys, 16 per iter.
// MFMA 16x16x32: A = Q-tile, B = K-tile,
//                D: lane l, reg r -> S[q0 + (l>>4)*4 + r][n0 + (l&15)].
// First 2 iterations fill the 32-slot pools directly (no ballot rounds);
// steady state: ballot-filtered replace-min with intra-quad butterfly argmin.
// ---------------------------------------------------------------------------
__global__ __launch_bounds__(256) void score_select_kernel(
    const unsigned short* __restrict__ qbf, const unsigned short* __restrict__ kbf,
    int* __restrict__ cand)
{
    __shared__ float pv[BQ][TOPK_N];    // 8 KB, wave-private rows
    __shared__ int   pix[BQ][TOPK_N];   // 8 KB

    const int tid  = threadIdx.x;
    const int wave = tid >> 6;
    const int lane = tid & 63;
    const int l16  = lane & 15;
    const int quad = lane >> 4;

    // XCD-aware remap (bijective): lin = 512*a + 8*b + c  ->  split = 2c + a,
    // qgrp = b.  Blocks with lin%8 == c all land on XCD c (round-robin
    // dispatch) and touch only splits {2c, 2c+1}.
    const int lin   = blockIdx.y * gridDim.x + blockIdx.x;   // [0, 1024)
    const int split = ((lin & 7) << 1) | (lin >> 9);
    const int qgrp  = (lin >> 3) & 63;
    const int q0    = qgrp * BQ + wave * 16;
    const int nbase = split * KPS;

    // A fragments (q-tile), resident for the whole kernel.
    short8 afrag[4];
#pragma unroll
    for (int t = 0; t < 4; ++t)
        afrag[t] = *(const short8*)(qbf + (size_t)(q0 + l16) * DKDIM + t * 32 + quad * 8);

    // ---- Fill phase: first 32 keys seed the 32 pool slots directly. ----
#pragma unroll
    for (int it = 0; it < 2; ++it) {
        const int n0 = nbase + it * 16;
        const unsigned short* kb = kbf + (size_t)(n0 + l16) * DKDIM + quad * 8;
        v4f acc = {0.f, 0.f, 0.f, 0.f};
#pragma unroll
        for (int t = 0; t < 4; ++t) {
            const short8 bfrag = *(const short8*)(kb + t * 32);
            acc = __builtin_amdgcn_mfma_f32_16x16x32_bf16(afrag[t], bfrag, acc, 0, 0, 0);
        }
#pragma unroll
        for (int r = 0; r < 4; ++r) {
            const int qq = wave * 16 + quad * 4 + r;
            pv[qq][it * 16 + l16]  = acc[r];
            pix[qq][it * 16 + l16] = n0 + l16;
        }
    }

    // Initial pool min/argmin per quad query (uniform across the quad).
    float vm[4]; int pp[4];
#pragma unroll
    for (int r = 0; r < 4; ++r) {
        const int qq = wave * 16 + quad * 4 + r;
        float s0 = pv[qq][l16];
        int   p0 = l16;
        const float s1 = pv[qq][l16 + 16];
        if (s1 < s0) { s0 = s1; p0 = l16 + 16; }
#pragma unroll
        for (int off = 1; off < 16; off <<= 1) {
            const float os = __shfl_xor(s0, off);
            const int   op = __shfl_xor(p0, off);
            if (os < s0) { s0 = os; p0 = op; }
        }
        vm[r] = s0; pp[r] = p0;
    }

    // ---- Steady state. ----
    for (int it = 2; it < KPS / 16; ++it) {
        const int n0 = nbase + it * 16;
        const unsigned short* kb = kbf + (size_t)(n0 + l16) * DKDIM + quad * 8;
        v4f acc = {0.f, 0.f, 0.f, 0.f};
#pragma unroll
        for (int t = 0; t < 4; ++t) {
            const short8 bfrag = *(const short8*)(kb + t * 32);
            acc = __builtin_amdgcn_mfma_f32_16x16x32_bf16(afrag[t], bfrag, acc, 0, 0, 0);
        }
#pragma unroll
        for (int r = 0; r < 4; ++r) {
            unsigned long long m = __ballot(acc[r] > vm[r]);
            while (m) {   // m wave-uniform
                // One hit per quad per round; clear mask computed uniformly.
                unsigned long long clearm = 0;
#pragma unroll
                for (int p = 0; p < 4; ++p) {
                    const unsigned int mp = (unsigned int)(m >> (p * 16)) & 0xFFFFu;
                    if (mp) clearm |= 1ULL << (p * 16 + __builtin_ctz(mp));
                }
                const unsigned int mq = (unsigned int)(m >> (quad * 16)) & 0xFFFFu;
                const bool has = (mq != 0);
                const int  src = has ? (quad * 16 + __builtin_ctz(mq)) : lane;
                const float v  = __shfl(acc[r], src);   // per-lane src (bpermute)
                if (has && v > vm[r]) {   // uniform within each quad
                    const int qq = wave * 16 + quad * 4 + r;
                    if (l16 == 0) { pv[qq][pp[r]] = v; pix[qq][pp[r]] = n0 + (src & 15); }
                    // Recompute pool argmin: 16 lanes x 2 slots + 4-step butterfly.
                    float s0 = pv[qq][l16];
                    int   p0 = l16;
                    const float s1 = pv[qq][l16 + 16];
                    if (s1 < s0) { s0 = s1; p0 = l16 + 16; }
#pragma unroll
                    for (int off = 1; off < 16; off <<= 1) {
                        const float os = __shfl_xor(s0, off);
                        const int   op = __shfl_xor(p0, off);
                        if (os < s0) { s0 = os; p0 = op; }
                    }
                    vm[r] = s0; pp[r] = p0;
                }
                m &= ~clearm;
            }
        }
    }

    // Writeout (pools are wave-private; no barrier needed).
    for (int i = lane; i < 16 * TOPK_N; i += 64) {
        const int qq = i >> 5, ss = i & 31;
        cand[((size_t)(q0 + qq) * NSPLIT + split) * TOPK_N + ss] = pix[wave * 16 + qq][ss];
    }
}

// ---------------------------------------------------------------------------
// Kernel C: exact fp32 rescore of 512 candidates (sequential fmaf chain,
// bitwise-matches reference), bitonic sort (desc, tie -> lower idx), gather.
// One block (512 threads) per query.
// ---------------------------------------------------------------------------
__global__ __launch_bounds__(512) void rescore_gather_kernel(
    const float* __restrict__ qg, const float* __restrict__ keys,
    const float* __restrict__ values, const int* __restrict__ cand,
    float* __restrict__ out)
{
    __shared__ float qrow[DKDIM];
    __shared__ float ss[NCAND];
    __shared__ int   si[NCAND];
    const int bt  = blockIdx.x;
    const int tid = threadIdx.x;

    if (tid < DKDIM) qrow[tid] = qg[(size_t)bt * DKDIM + tid];
    __syncthreads();

    const int idx = cand[(size_t)bt * NCAND + tid];
    const float4* krow = (const float4*)(keys + (size_t)idx * DKDIM);
    float s = 0.f;
#pragma unroll
    for (int d4 = 0; d4 < DKDIM / 4; ++d4) {
        const float4 k4 = krow[d4];
        const float4 q4 = *(const float4*)&qrow[4 * d4];
        s = fmaf(q4.x, k4.x, s);
        s = fmaf(q4.y, k4.y, s);
        s = fmaf(q4.z, k4.z, s);
        s = fmaf(q4.w, k4.w, s);
    }
    ss[tid] = s; si[tid] = idx;
    __syncthreads();

    for (int k = 2; k <= NCAND; k <<= 1) {
        for (int j = k >> 1; j > 0; j >>= 1) {
            const int ixj = tid ^ j;
            if (ixj > tid) {
                const bool dirDesc = ((tid & k) == 0);
                const float sa = ss[tid], sb = ss[ixj];
                const int   ia = si[tid], ib = si[ixj];
                const bool before = (sa > sb) || (sa == sb && ia < ib);
                if (before != dirDesc) {
                    ss[tid] = sb; ss[ixj] = sa;
                    si[tid] = ib; si[ixj] = ia;
                }
            }
            __syncthreads();
        }
    }

    const int lane = tid & 31;
    const int rb   = tid >> 5;          // [0, 16)
#pragma unroll
    for (int r = 0; r < 2; ++r) {
        const int row = rb + 16 * r;
        const int n   = si[row];
        const float4 kv = *(const float4*)(keys   + (size_t)n * DKDIM + 4 * lane);
        const float4 vv = *(const float4*)(values + (size_t)n * DVDIM + 4 * lane);
        const size_t ob = ((size_t)bt * TOPK_N + row) * DKDIM + 4 * lane;
        *(float4*)(out + ob)        = kv;
        *(float4*)(out + NOUT + ob) = vv;
    }
}

extern "C" void kernel_launch(void* const* d_in, const int* in_sizes, int n_in,
                              void* d_out, int out_size, void* d_ws, size_t ws_size,
                              hipStream_t stream)
{
    const float* q      = (const float*)d_in[0];
    const float* keys   = (const float*)d_in[1];
    const float* values = (const float*)d_in[2];
    float* out = (float*)d_out;

    unsigned short* qbf = (unsigned short*)d_ws;                               // 1 MB
    unsigned short* kbf = (unsigned short*)((char*)d_ws + (1u << 20));         // 16 MB
    int* cand = (int*)((char*)d_ws + (17u << 20));                             // 8 MB

    const int cvt_groups = (NQ + NKEYS) * DKDIM / 8;
    convert_kernel<<<(cvt_groups + 255) / 256, 256, 0, stream>>>(q, keys, qbf, kbf);
    score_select_kernel<<<dim3(NQ / BQ, NSPLIT), 256, 0, stream>>>(qbf, kbf, cand);
    rescore_gather_kernel<<<NQ, 512, 0, stream>>>(q, keys, values, cand, out);
}

// Round 3
// 891.098 us; speedup vs baseline: 1.3923x; 1.2981x over previous
//
#include <hip/hip_runtime.h>
#include <float.h>

#define NQ      4096
#define NKEYS   65536
#define DKDIM   128
#define DVDIM   128
#define TOPK_N  32
#define NSPLIT  16
#define KPS     (NKEYS / NSPLIT)        // 4096 keys per split
#define BQ      64                      // queries per block (4 waves x 16)
#define NCAND   (NSPLIT * TOPK_N)       // 512 candidates per query
#define NOUT    ((size_t)NQ * TOPK_N * DKDIM)

typedef __attribute__((ext_vector_type(8))) short short8;   // 8 bf16
typedef __attribute__((ext_vector_type(4))) float v4f;      // MFMA acc

__device__ inline unsigned short f2bf(float f) {            // RNE fp32->bf16
    unsigned int u = __float_as_uint(f);
    return (unsigned short)((u + 0x7FFFu + ((u >> 16) & 1u)) >> 16);
}

// Cross-lane compare-exchange (within 16-lane quad; s < 16).
// Sorts descending when desc==true, ties -> lower idx first.
#define CEXX(v, id, s, desc) {                                              \
    const float _ov = __shfl_xor((v), (s));                                 \
    const int   _oi = __shfl_xor((id), (s));                                \
    const bool _first = ((v) > _ov) || ((v) == _ov && (id) < _oi);          \
    const bool _keep  = (_first == (((l16 & (s)) == 0) == (desc)));         \
    (v) = _keep ? (v) : _ov; (id) = _keep ? (id) : _oi; }

// Intra-lane compare-exchange, descending (low position keeps the larger).
#define CEXI(va, ia, vb, ib) {                                              \
    const bool _f = ((va) > (vb)) || ((va) == (vb) && (ia) < (ib));         \
    if (!_f) { const float _tv=(va); (va)=(vb); (vb)=_tv;                   \
               const int _ti=(ia); (ia)=(ib); (ib)=_ti; } }

// Compact: bitonic-sort the <=32-item append region (LDS), bitonic-merge
// with the register-resident sorted pool (pv0/pv1 desc over slot l16,
// 16+l16), keep top-32 in pool, reset count, refresh vm (pool min).
__device__ __forceinline__ void sortmerge(
    float& pv0, float& pv1, int& pi0, int& pi1,
    float& vmr, int& cc,
    const float* __restrict__ bvq, const int* __restrict__ biq,
    const int l16, const int lane)
{
    // Load append region, item index a = j*16 + l16; pad with -inf.
    float s0 = (l16      < cc) ? bvq[l16]      : -FLT_MAX;
    float s1 = (l16 + 16 < cc) ? bvq[l16 + 16] : -FLT_MAX;
    int   t0 = (l16      < cc) ? biq[l16]      : 0x7FFFFFFF;
    int   t1 = (l16 + 16 < cc) ? biq[l16 + 16] : 0x7FFFFFFF;

    // Bitonic sort-32, descending (mirrored network: desc = ((a&k)==0)).
    CEXX(s0, t0, 1, ((l16 & 2) == 0)); CEXX(s1, t1, 1, ((l16 & 2) == 0));   // k=2
    CEXX(s0, t0, 2, ((l16 & 4) == 0)); CEXX(s1, t1, 2, ((l16 & 4) == 0));   // k=4
    CEXX(s0, t0, 1, ((l16 & 4) == 0)); CEXX(s1, t1, 1, ((l16 & 4) == 0));
    CEXX(s0, t0, 4, ((l16 & 8) == 0)); CEXX(s1, t1, 4, ((l16 & 8) == 0));   // k=8
    CEXX(s0, t0, 2, ((l16 & 8) == 0)); CEXX(s1, t1, 2, ((l16 & 8) == 0));
    CEXX(s0, t0, 1, ((l16 & 8) == 0)); CEXX(s1, t1, 1, ((l16 & 8) == 0));
    CEXX(s0, t0, 8, true);  CEXX(s1, t1, 8, false);                         // k=16
    CEXX(s0, t0, 4, true);  CEXX(s1, t1, 4, false);
    CEXX(s0, t0, 2, true);  CEXX(s1, t1, 2, false);
    CEXX(s0, t0, 1, true);  CEXX(s1, t1, 1, false);
    CEXI(s0, t0, s1, t1);                                                   // k=32, s=16
    CEXX(s0, t0, 8, true);  CEXX(s1, t1, 8, true);
    CEXX(s0, t0, 4, true);  CEXX(s1, t1, 4, true);
    CEXX(s0, t0, 2, true);  CEXX(s1, t1, 2, true);
    CEXX(s0, t0, 1, true);  CEXX(s1, t1, 1, true);

    // Reverse appended (desc -> asc) to form a bitonic 64-sequence with pool.
    float c0 = __shfl_xor(s1, 15); int d0 = __shfl_xor(t1, 15);
    float c1 = __shfl_xor(s0, 15); int d1 = __shfl_xor(t0, 15);

    // Descending bitonic clean of 64 = {pv0(i=l16), pv1(16+l16), c0(32+l16),
    // c1(48+l16)}; after s=32..1 the top half (pv0,pv1) is the sorted top-32.
    CEXI(pv0, pi0, c0, d0);            // s=32
    CEXI(pv1, pi1, c1, d1);
    CEXI(pv0, pi0, pv1, pi1);          // s=16
    CEXI(c0, d0, c1, d1);
    CEXX(pv0, pi0, 8, true); CEXX(pv1, pi1, 8, true);
    CEXX(c0, d0, 8, true);   CEXX(c1, d1, 8, true);
    CEXX(pv0, pi0, 4, true); CEXX(pv1, pi1, 4, true);
    CEXX(c0, d0, 4, true);   CEXX(c1, d1, 4, true);
    CEXX(pv0, pi0, 2, true); CEXX(pv1, pi1, 2, true);
    CEXX(c0, d0, 2, true);   CEXX(c1, d1, 2, true);
    CEXX(pv0, pi0, 1, true); CEXX(pv1, pi1, 1, true);
    CEXX(c0, d0, 1, true);   CEXX(c1, d1, 1, true);

    cc  = 0;
    vmr = __shfl(pv1, (lane & 48) | 15);   // pool min = slot 31
}

// ---------------------------------------------------------------------------
// Kernel A: convert q and keys to bf16 (workspace).
// ---------------------------------------------------------------------------
__global__ __launch_bounds__(256) void convert_kernel(
    const float* __restrict__ q, const float* __restrict__ keys,
    unsigned short* __restrict__ qbf, unsigned short* __restrict__ kbf)
{
    const size_t QG = (size_t)NQ * DKDIM / 8;       // 65536 groups of 8
    const size_t KG = (size_t)NKEYS * DKDIM / 8;    // 1048576
    const size_t g  = (size_t)blockIdx.x * 256 + threadIdx.x;
    if (g >= QG + KG) return;
    const float* src;
    unsigned short* dst;
    if (g < QG) { src = q + g * 8;         dst = qbf + g * 8; }
    else        { const size_t h = g - QG; src = keys + h * 8; dst = kbf + h * 8; }
    const float4 a = ((const float4*)src)[0];
    const float4 b = ((const float4*)src)[1];
    short8 o;
    o[0] = (short)f2bf(a.x); o[1] = (short)f2bf(a.y);
    o[2] = (short)f2bf(a.z); o[3] = (short)f2bf(a.w);
    o[4] = (short)f2bf(b.x); o[5] = (short)f2bf(b.y);
    o[6] = (short)f2bf(b.z); o[7] = (short)f2bf(b.w);
    *(short8*)dst = o;
}

// ---------------------------------------------------------------------------
// Kernel B: bf16 MFMA approx scores + per-(query,split) exact top-32 via
// append-buffer + periodic bitonic sort-merge.
// Grid (NQ/BQ, NSPLIT) remapped so each XCD (lin%8) owns 2 splits ->
// kbf slice (2 MB) + qbf (1 MB) stay L2-resident per XCD.
// Block 256 = 4 waves; wave w owns queries [qgrp*64 + 16w, +16).
// MFMA 16x16x32: D: lane l, reg r -> S[q0 + (l>>4)*4 + r][n0 + (l&15)].
// Selection: pool top-32 in registers (sorted desc), vm = pool min (stale
// between compactions -> admits supersets, safe). Hits append in parallel
// at ballot-prefix positions; wave-uniform compaction when any quad's
// buffer would overflow. Exact per-split top-32 at the end.
// ---------------------------------------------------------------------------
__global__ __launch_bounds__(256) void score_select_kernel(
    const unsigned short* __restrict__ qbf, const unsigned short* __restrict__ kbf,
    int* __restrict__ cand)
{
    __shared__ float bv[BQ][32];    // 8 KB append buffers (quad-private rows)
    __shared__ int   bi[BQ][32];    // 8 KB

    const int tid  = threadIdx.x;
    const int wave = tid >> 6;
    const int lane = tid & 63;
    const int l16  = lane & 15;
    const int quad = lane >> 4;

    // XCD-aware remap (bijective): lin = 512*a + 8*b + c  ->  split = 2c + a,
    // qgrp = b.  Blocks with lin%8 == c all land on XCD c and touch only
    // splits {2c, 2c+1}.
    const int lin   = blockIdx.y * gridDim.x + blockIdx.x;   // [0, 1024)
    const int split = ((lin & 7) << 1) | (lin >> 9);
    const int qgrp  = (lin >> 3) & 63;
    const int q0    = qgrp * BQ + wave * 16;
    const int nbase = split * KPS;

    float* bvq = &bv[wave * 16 + quad * 4][0];   // row base; row r at +r*32
    int*   biq = &bi[wave * 16 + quad * 4][0];

    // A fragments (q-tile), resident for the whole kernel.
    short8 afrag[4];
#pragma unroll
    for (int t = 0; t < 4; ++t)
        afrag[t] = *(const short8*)(qbf + (size_t)(q0 + l16) * DKDIM + t * 32 + quad * 8);

    // Register pool (sorted desc; slots l16 and 16+l16) + stale min + count.
    float pv0[4], pv1[4], vm[4];
    int   pi0[4], pi1[4], ccnt[4];
#pragma unroll
    for (int r = 0; r < 4; ++r) {
        pv0[r] = pv1[r] = vm[r] = -FLT_MAX;
        pi0[r] = pi1[r] = 0; ccnt[r] = 0;
    }

    const unsigned short* kb = kbf + (size_t)(nbase + l16) * DKDIM + quad * 8;
    for (int it = 0; it < KPS / 16; ++it, kb += 16 * DKDIM) {
        const int n0 = nbase + it * 16;
        v4f acc = {0.f, 0.f, 0.f, 0.f};
#pragma unroll
        for (int t = 0; t < 4; ++t) {
            const short8 bfrag = *(const short8*)(kb + t * 32);
            acc = __builtin_amdgcn_mfma_f32_16x16x32_bf16(afrag[t], bfrag, acc, 0, 0, 0);
        }
#pragma unroll
        for (int r = 0; r < 4; ++r) {
            const bool hit = acc[r] > vm[r];
            const unsigned long long mb = __ballot(hit);
            const unsigned int mq = (unsigned int)(mb >> (quad * 16)) & 0xFFFFu;
            const int nh = __popc(mq);
            if (__ballot(ccnt[r] + nh > 32)) {      // wave-uniform compaction
                sortmerge(pv0[r], pv1[r], pi0[r], pi1[r], vm[r], ccnt[r],
                          bvq + r * 32, biq + r * 32, l16, lane);
            }
            if (hit) {                               // parallel append
                const int pos = ccnt[r] + __popc(mq & ((1u << l16) - 1u));
                (bvq + r * 32)[pos] = acc[r];
                (biq + r * 32)[pos] = n0 + l16;
            }
            ccnt[r] += nh;
        }
    }

    // Final flush + writeout (pool sorted desc; kernel C re-sorts anyway).
#pragma unroll
    for (int r = 0; r < 4; ++r) {
        sortmerge(pv0[r], pv1[r], pi0[r], pi1[r], vm[r], ccnt[r],
                  bvq + r * 32, biq + r * 32, l16, lane);
        const size_t base = ((size_t)(q0 + quad * 4 + r) * NSPLIT + split) * TOPK_N;
        cand[base + l16]      = pi0[r];
        cand[base + 16 + l16] = pi1[r];
    }
}

// ---------------------------------------------------------------------------
// Kernel C: exact fp32 rescore of 512 candidates (sequential fmaf chain,
// bitwise-matches reference), bitonic sort (desc, tie -> lower idx), gather.
// One block (512 threads) per query.
// ---------------------------------------------------------------------------
__global__ __launch_bounds__(512) void rescore_gather_kernel(
    const float* __restrict__ qg, const float* __restrict__ keys,
    const float* __restrict__ values, const int* __restrict__ cand,
    float* __restrict__ out)
{
    __shared__ float qrow[DKDIM];
    __shared__ float ss[NCAND];
    __shared__ int   si[NCAND];
    const int bt  = blockIdx.x;
    const int tid = threadIdx.x;

    if (tid < DKDIM) qrow[tid] = qg[(size_t)bt * DKDIM + tid];
    __syncthreads();

    const int idx = cand[(size_t)bt * NCAND + tid];
    const float4* krow = (const float4*)(keys + (size_t)idx * DKDIM);
    float s = 0.f;
#pragma unroll
    for (int d4 = 0; d4 < DKDIM / 4; ++d4) {
        const float4 k4 = krow[d4];
        const float4 q4 = *(const float4*)&qrow[4 * d4];
        s = fmaf(q4.x, k4.x, s);
        s = fmaf(q4.y, k4.y, s);
        s = fmaf(q4.z, k4.z, s);
        s = fmaf(q4.w, k4.w, s);
    }
    ss[tid] = s; si[tid] = idx;
    __syncthreads();

    for (int k = 2; k <= NCAND; k <<= 1) {
        for (int j = k >> 1; j > 0; j >>= 1) {
            const int ixj = tid ^ j;
            if (ixj > tid) {
                const bool dirDesc = ((tid & k) == 0);
                const float sa = ss[tid], sb = ss[ixj];
                const int   ia = si[tid], ib = si[ixj];
                const bool before = (sa > sb) || (sa == sb && ia < ib);
                if (before != dirDesc) {
                    ss[tid] = sb; ss[ixj] = sa;
                    si[tid] = ib; si[ixj] = ia;
                }
            }
            __syncthreads();
        }
    }

    const int lane = tid & 31;
    const int rb   = tid >> 5;          // [0, 16)
#pragma unroll
    for (int r = 0; r < 2; ++r) {
        const int row = rb + 16 * r;
        const int n   = si[row];
        const float4 kv = *(const float4*)(keys   + (size_t)n * DKDIM + 4 * lane);
        const float4 vv = *(const float4*)(values + (size_t)n * DVDIM + 4 * lane);
        const size_t ob = ((size_t)bt * TOPK_N + row) * DKDIM + 4 * lane;
        *(float4*)(out + ob)        = kv;
        *(float4*)(out + NOUT + ob) = vv;
    }
}

extern "C" void kernel_launch(void* const* d_in, const int* in_sizes, int n_in,
                              void* d_out, int out_size, void* d_ws, size_t ws_size,
                              hipStream_t stream)
{
    const float* q      = (const float*)d_in[0];
    const float* keys   = (const float*)d_in[1];
    const float* values = (const float*)d_in[2];
    float* out = (float*)d_out;

    unsigned short* qbf = (unsigned short*)d_ws;                               // 1 MB
    unsigned short* kbf = (unsigned short*)((char*)d_ws + (1u << 20));         // 16 MB
    int* cand = (int*)((char*)d_ws + (17u << 20));                             // 8 MB

    const int cvt_groups = (NQ + NKEYS) * DKDIM / 8;
    convert_kernel<<<(cvt_groups + 255) / 256, 256, 0, stream>>>(q, keys, qbf, kbf);
    score_select_kernel<<<dim3(NQ / BQ, NSPLIT), 256, 0, stream>>>(qbf, kbf, cand);
    rescore_gather_kernel<<<NQ, 512, 0, stream>>>(q, keys, values, cand, out);
}

// Round 4
// 888.435 us; speedup vs baseline: 1.3965x; 1.0030x over previous
//
#include <hip/hip_runtime.h>
#include <float.h>

#define NQ      4096
#define NKEYS   65536
#define DKDIM   128
#define DVDIM   128
#define TOPK_N  32
#define NSPLIT  16
#define KPS     (NKEYS / NSPLIT)        // 4096 keys per split
#define BQ      64                      // queries per block (4 waves x 16)
#define NCAND   (NSPLIT * TOPK_N)       // 512 candidates per query
#define NOUT    ((size_t)NQ * TOPK_N * DKDIM)
#define NIT     (KPS / 16)              // 256 16-key tiles per split

typedef __attribute__((ext_vector_type(8))) short short8;   // 8 bf16
typedef __attribute__((ext_vector_type(4))) float v4f;      // MFMA acc

__device__ inline unsigned short f2bf(float f) {            // RNE fp32->bf16
    unsigned int u = __float_as_uint(f);
    return (unsigned short)((u + 0x7FFFu + ((u >> 16) & 1u)) >> 16);
}

// Cross-lane compare-exchange (within 16-lane quad; s < 16).
// Sorts descending when desc==true, ties -> lower idx first.
#define CEXX(v, id, s, desc) {                                              \
    const float _ov = __shfl_xor((v), (s));                                 \
    const int   _oi = __shfl_xor((id), (s));                                \
    const bool _first = ((v) > _ov) || ((v) == _ov && (id) < _oi);          \
    const bool _keep  = (_first == (((l16 & (s)) == 0) == (desc)));         \
    (v) = _keep ? (v) : _ov; (id) = _keep ? (id) : _oi; }

// Intra-lane compare-exchange, descending (low position keeps the larger).
#define CEXI(va, ia, vb, ib) {                                              \
    const bool _f = ((va) > (vb)) || ((va) == (vb) && (ia) < (ib));         \
    if (!_f) { const float _tv=(va); (va)=(vb); (vb)=_tv;                   \
               const int _ti=(ia); (ia)=(ib); (ib)=_ti; } }

// Compact one query's buffer (row pointers, old quad-orientation: lanes of a
// quad cooperate on query quad*4+r): bitonic-sort the <=32-item append region
// (LDS), bitonic-merge with the register-resident sorted pool (pv0/pv1 desc
// over slots l16, 16+l16), keep top-32 in pool.  [verified network, round 3]
__device__ __forceinline__ void sortmerge(
    float& pv0, float& pv1, int& pi0, int& pi1, const int cc,
    const float* __restrict__ bvr, const int* __restrict__ bir, const int l16)
{
    // Load append region, item index a = j*16 + l16; pad with -inf.
    float s0 = (l16      < cc) ? bvr[l16]      : -FLT_MAX;
    float s1 = (l16 + 16 < cc) ? bvr[l16 + 16] : -FLT_MAX;
    int   t0 = (l16      < cc) ? bir[l16]      : 0x7FFFFFFF;
    int   t1 = (l16 + 16 < cc) ? bir[l16 + 16] : 0x7FFFFFFF;

    // Bitonic sort-32, descending (mirrored network: desc = ((a&k)==0)).
    CEXX(s0, t0, 1, ((l16 & 2) == 0)); CEXX(s1, t1, 1, ((l16 & 2) == 0));   // k=2
    CEXX(s0, t0, 2, ((l16 & 4) == 0)); CEXX(s1, t1, 2, ((l16 & 4) == 0));   // k=4
    CEXX(s0, t0, 1, ((l16 & 4) == 0)); CEXX(s1, t1, 1, ((l16 & 4) == 0));
    CEXX(s0, t0, 4, ((l16 & 8) == 0)); CEXX(s1, t1, 4, ((l16 & 8) == 0));   // k=8
    CEXX(s0, t0, 2, ((l16 & 8) == 0)); CEXX(s1, t1, 2, ((l16 & 8) == 0));
    CEXX(s0, t0, 1, ((l16 & 8) == 0)); CEXX(s1, t1, 1, ((l16 & 8) == 0));
    CEXX(s0, t0, 8, true);  CEXX(s1, t1, 8, false);                         // k=16
    CEXX(s0, t0, 4, true);  CEXX(s1, t1, 4, false);
    CEXX(s0, t0, 2, true);  CEXX(s1, t1, 2, false);
    CEXX(s0, t0, 1, true);  CEXX(s1, t1, 1, false);
    CEXI(s0, t0, s1, t1);                                                   // k=32, s=16
    CEXX(s0, t0, 8, true);  CEXX(s1, t1, 8, true);
    CEXX(s0, t0, 4, true);  CEXX(s1, t1, 4, true);
    CEXX(s0, t0, 2, true);  CEXX(s1, t1, 2, true);
    CEXX(s0, t0, 1, true);  CEXX(s1, t1, 1, true);

    // Reverse appended (desc -> asc) to form a bitonic 64-sequence with pool.
    float c0 = __shfl_xor(s1, 15); int d0 = __shfl_xor(t1, 15);
    float c1 = __shfl_xor(s0, 15); int d1 = __shfl_xor(t0, 15);

    // Descending bitonic clean of 64 = {pv0(i=l16), pv1(16+l16), c0(32+l16),
    // c1(48+l16)}; after s=32..1 the top half (pv0,pv1) is the sorted top-32.
    CEXI(pv0, pi0, c0, d0);            // s=32
    CEXI(pv1, pi1, c1, d1);
    CEXI(pv0, pi0, pv1, pi1);          // s=16
    CEXI(c0, d0, c1, d1);
    CEXX(pv0, pi0, 8, true); CEXX(pv1, pi1, 8, true);
    CEXX(c0, d0, 8, true);   CEXX(c1, d1, 8, true);
    CEXX(pv0, pi0, 4, true); CEXX(pv1, pi1, 4, true);
    CEXX(c0, d0, 4, true);   CEXX(c1, d1, 4, true);
    CEXX(pv0, pi0, 2, true); CEXX(pv1, pi1, 2, true);
    CEXX(c0, d0, 2, true);   CEXX(c1, d1, 2, true);
    CEXX(pv0, pi0, 1, true); CEXX(pv1, pi1, 1, true);
    CEXX(c0, d0, 1, true);   CEXX(c1, d1, 1, true);
}

// ---------------------------------------------------------------------------
// Kernel A: convert q and keys to bf16 (workspace).
// ---------------------------------------------------------------------------
__global__ __launch_bounds__(256) void convert_kernel(
    const float* __restrict__ q, const float* __restrict__ keys,
    unsigned short* __restrict__ qbf, unsigned short* __restrict__ kbf)
{
    const size_t QG = (size_t)NQ * DKDIM / 8;       // 65536 groups of 8
    const size_t KG = (size_t)NKEYS * DKDIM / 8;    // 1048576
    const size_t g  = (size_t)blockIdx.x * 256 + threadIdx.x;
    if (g >= QG + KG) return;
    const float* src;
    unsigned short* dst;
    if (g < QG) { src = q + g * 8;         dst = qbf + g * 8; }
    else        { const size_t h = g - QG; src = keys + h * 8; dst = kbf + h * 8; }
    const float4 a = ((const float4*)src)[0];
    const float4 b = ((const float4*)src)[1];
    short8 o;
    o[0] = (short)f2bf(a.x); o[1] = (short)f2bf(a.y);
    o[2] = (short)f2bf(a.z); o[3] = (short)f2bf(a.w);
    o[4] = (short)f2bf(b.x); o[5] = (short)f2bf(b.y);
    o[6] = (short)f2bf(b.z); o[7] = (short)f2bf(b.w);
    *(short8*)dst = o;
}

// ---------------------------------------------------------------------------
// Kernel B: transposed-MFMA bf16 approx scores + per-(query,split) exact
// top-32 via append-buffer + periodic bitonic sort-merge.
// Grid (NQ/BQ, NSPLIT) remapped so each XCD (lin%8) owns 2 splits ->
// kbf slice (2 MB) + qbf (1 MB) stay L2-resident per XCD.
// Block 256 = 4 waves; wave w owns queries [qgrp*64 + 16w, +16).
// MFMA 16x16x32 with A=K-tile, B=Q-tile -> D is S^T:
//   lane l, reg r -> S[key n0 + (l>>4)*4 + r][query q0 + (l&15)].
// Each lane owns query q0+l16: 4 compares, cross-quad count via 2 shfl_xor,
// parallel append at prefix position, ONE overflow ballot per 16 keys.
// Compaction (pool regs + sortmerge + writeout) stays in the verified
// quad-orientation; counts/pool-min are redistributed via shfls.
// ---------------------------------------------------------------------------
__global__ __launch_bounds__(256, 4) void score_select_kernel(
    const unsigned short* __restrict__ qbf, const unsigned short* __restrict__ kbf,
    int* __restrict__ cand)
{
    __shared__ float bv[BQ][33];    // padded append buffers (row = query)
    __shared__ int   bi[BQ][33];

    const int tid  = threadIdx.x;
    const int wave = tid >> 6;
    const int lane = tid & 63;
    const int l16  = lane & 15;
    const int quad = lane >> 4;

    // XCD-aware remap (bijective): lin = 512*a + 8*b + c  ->  split = 2c + a,
    // qgrp = b.  Blocks with lin%8 == c all land on XCD c and touch only
    // splits {2c, 2c+1}.
    const int lin   = blockIdx.y * gridDim.x + blockIdx.x;   // [0, 1024)
    const int split = ((lin & 7) << 1) | (lin >> 9);
    const int qgrp  = (lin >> 3) & 63;
    const int q0    = qgrp * BQ + wave * 16;
    const int nbase = split * KPS;

    float* __restrict__ bvq = &bv[wave * 16 + l16][0];   // this lane's query row
    int*   __restrict__ biq = &bi[wave * 16 + l16][0];

    // Q fragments (B-operand), resident for the whole kernel (same layout as
    // the verified orientation: lane holds Q[q0+l16][quad*8 + 32t + j]).
    short8 afrag[4];
#pragma unroll
    for (int t = 0; t < 4; ++t)
        afrag[t] = *(const short8*)(qbf + (size_t)(q0 + l16) * DKDIM + t * 32 + quad * 8);

    // Register pool in quad-orientation (query quad*4+r; sorted desc over
    // slots l16, 16+l16).  vmq/cnt in lane-orientation (query l16),
    // replicated across quads.
    float pv0[4], pv1[4];
    int   pi0[4], pi1[4];
#pragma unroll
    for (int r = 0; r < 4; ++r) { pv0[r] = pv1[r] = -FLT_MAX; pi0[r] = pi1[r] = 0; }
    float vmq = -FLT_MAX;
    int   cnt = 0;

    const unsigned short* kb = kbf + (size_t)(nbase + l16) * DKDIM + quad * 8;

    auto select16 = [&](const v4f acc, const int n0) {
        // Per-lane hits: 4 keys (n0 + quad*4 + r) of query l16.
        const int h0 = acc[0] > vmq;
        const int h1 = acc[1] > vmq;
        const int h2 = acc[2] > vmq;
        const int h3 = acc[3] > vmq;
        const int nh = h0 + h1 + h2 + h3;
        // Cross-quad (stride-16/32) sum + prefix for this query column.
        const int s16   = __shfl_xor(nh, 16);
        const int psum  = nh + s16;
        const int sx32  = __shfl_xor(psum, 32);
        const int nhcol = psum + sx32;
        if (__ballot(cnt + nhcol > 32)) {            // wave-uniform compaction
#pragma unroll
            for (int r = 0; r < 4; ++r) {
                const int cc = __shfl(cnt, quad * 4 + r);
                const int qq = wave * 16 + quad * 4 + r;
                sortmerge(pv0[r], pv1[r], pi0[r], pi1[r], cc, &bv[qq][0], &bi[qq][0], l16);
            }
            // Redistribute pool-min (slot 31 = pv1 at l16==15 of owner quad)
            // from quad-orientation to lane-orientation (query l16).
            const float t0v = __shfl(pv1[0], (l16 >> 2) * 16 + 15);
            const float t1v = __shfl(pv1[1], (l16 >> 2) * 16 + 15);
            const float t2v = __shfl(pv1[2], (l16 >> 2) * 16 + 15);
            const float t3v = __shfl(pv1[3], (l16 >> 2) * 16 + 15);
            const float a01 = (l16 & 1) ? t1v : t0v;
            const float a23 = (l16 & 1) ? t3v : t2v;
            vmq = (l16 & 2) ? a23 : a01;
            cnt = 0;
        }
        // Parallel append (old-vm hits; superset of true top-32 is safe).
        int pos = cnt + ((quad & 1) ? s16 : 0) + ((quad & 2) ? sx32 : 0);
        if (h0) { bvq[pos] = acc[0]; biq[pos] = n0 + quad * 4;     ++pos; }
        if (h1) { bvq[pos] = acc[1]; biq[pos] = n0 + quad * 4 + 1; ++pos; }
        if (h2) { bvq[pos] = acc[2]; biq[pos] = n0 + quad * 4 + 2; ++pos; }
        if (h3) { bvq[pos] = acc[3]; biq[pos] = n0 + quad * 4 + 3; }
        cnt += nhcol;
    };

    // 2-deep copy-free prefetch: tiles it, it+1 resident; prefetch it+2/it+3
    // right after their registers are consumed.  Tail prefetch reads at most
    // 2 tiles (8 KB) past the split end -- lands in kbf/cand workspace, safe.
    short8 cA[4], cB[4];
#pragma unroll
    for (int t = 0; t < 4; ++t) cA[t] = *(const short8*)(kb + t * 32);
    kb += 16 * DKDIM;
#pragma unroll
    for (int t = 0; t < 4; ++t) cB[t] = *(const short8*)(kb + t * 32);
    kb += 16 * DKDIM;

    for (int it = 0; it < NIT; it += 2) {
        v4f acc = {0.f, 0.f, 0.f, 0.f};
#pragma unroll
        for (int t = 0; t < 4; ++t)   // A = K-tile, B = Q-tile  ->  S^T
            acc = __builtin_amdgcn_mfma_f32_16x16x32_bf16(cA[t], afrag[t], acc, 0, 0, 0);
#pragma unroll
        for (int t = 0; t < 4; ++t) cA[t] = *(const short8*)(kb + t * 32);
        kb += 16 * DKDIM;
        select16(acc, nbase + it * 16);

        v4f acc2 = {0.f, 0.f, 0.f, 0.f};
#pragma unroll
        for (int t = 0; t < 4; ++t)
            acc2 = __builtin_amdgcn_mfma_f32_16x16x32_bf16(cB[t], afrag[t], acc2, 0, 0, 0);
#pragma unroll
        for (int t = 0; t < 4; ++t) cB[t] = *(const short8*)(kb + t * 32);
        kb += 16 * DKDIM;
        select16(acc2, nbase + it * 16 + 16);
    }

    // Final flush + writeout (quad-orientation; pool sorted desc).
#pragma unroll
    for (int r = 0; r < 4; ++r) {
        const int cc = __shfl(cnt, quad * 4 + r);
        const int qq = wave * 16 + quad * 4 + r;
        sortmerge(pv0[r], pv1[r], pi0[r], pi1[r], cc, &bv[qq][0], &bi[qq][0], l16);
        const size_t base = ((size_t)(q0 + quad * 4 + r) * NSPLIT + split) * TOPK_N;
        cand[base + l16]      = pi0[r];
        cand[base + 16 + l16] = pi1[r];
    }
}

// ---------------------------------------------------------------------------
// Kernel C: exact fp32 rescore of 512 candidates (sequential fmaf chain,
// bitwise-matches reference), bitonic sort (desc, tie -> lower idx), gather.
// One block (512 threads) per query.
// ---------------------------------------------------------------------------
__global__ __launch_bounds__(512) void rescore_gather_kernel(
    const float* __restrict__ qg, const float* __restrict__ keys,
    const float* __restrict__ values, const int* __restrict__ cand,
    float* __restrict__ out)
{
    __shared__ float qrow[DKDIM];
    __shared__ float ss[NCAND];
    __shared__ int   si[NCAND];
    const int bt  = blockIdx.x;
    const int tid = threadIdx.x;

    if (tid < DKDIM) qrow[tid] = qg[(size_t)bt * DKDIM + tid];
    __syncthreads();

    const int idx = cand[(size_t)bt * NCAND + tid];
    const float4* krow = (const float4*)(keys + (size_t)idx * DKDIM);
    float s = 0.f;
#pragma unroll
    for (int d4 = 0; d4 < DKDIM / 4; ++d4) {
        const float4 k4 = krow[d4];
        const float4 q4 = *(const float4*)&qrow[4 * d4];
        s = fmaf(q4.x, k4.x, s);
        s = fmaf(q4.y, k4.y, s);
        s = fmaf(q4.z, k4.z, s);
        s = fmaf(q4.w, k4.w, s);
    }
    ss[tid] = s; si[tid] = idx;
    __syncthreads();

    for (int k = 2; k <= NCAND; k <<= 1) {
        for (int j = k >> 1; j > 0; j >>= 1) {
            const int ixj = tid ^ j;
            if (ixj > tid) {
                const bool dirDesc = ((tid & k) == 0);
                const float sa = ss[tid], sb = ss[ixj];
                const int   ia = si[tid], ib = si[ixj];
                const bool before = (sa > sb) || (sa == sb && ia < ib);
                if (before != dirDesc) {
                    ss[tid] = sb; ss[ixj] = sa;
                    si[tid] = ib; si[ixj] = ia;
                }
            }
            __syncthreads();
        }
    }

    const int lane = tid & 31;
    const int rb   = tid >> 5;          // [0, 16)
#pragma unroll
    for (int r = 0; r < 2; ++r) {
        const int row = rb + 16 * r;
        const int n   = si[row];
        const float4 kv = *(const float4*)(keys   + (size_t)n * DKDIM + 4 * lane);
        const float4 vv = *(const float4*)(values + (size_t)n * DVDIM + 4 * lane);
        const size_t ob = ((size_t)bt * TOPK_N + row) * DKDIM + 4 * lane;
        *(float4*)(out + ob)        = kv;
        *(float4*)(out + NOUT + ob) = vv;
    }
}

extern "C" void kernel_launch(void* const* d_in, const int* in_sizes, int n_in,
                              void* d_out, int out_size, void* d_ws, size_t ws_size,
                              hipStream_t stream)
{
    const float* q      = (const float*)d_in[0];
    const float* keys   = (const float*)d_in[1];
    const float* values = (const float*)d_in[2];
    float* out = (float*)d_out;

    unsigned short* qbf = (unsigned short*)d_ws;                               // 1 MB
    unsigned short* kbf = (unsigned short*)((char*)d_ws + (1u << 20));         // 16 MB
    int* cand = (int*)((char*)d_ws + (17u << 20));                             // 8 MB

    const int cvt_groups = (NQ + NKEYS) * DKDIM / 8;
    convert_kernel<<<(cvt_groups + 255) / 256, 256, 0, stream>>>(q, keys, qbf, kbf);
    score_select_kernel<<<dim3(NQ / BQ, NSPLIT), 256, 0, stream>>>(qbf, kbf, cand);
    rescore_gather_kernel<<<NQ, 512, 0, stream>>>(q, keys, values, cand, out);
}

// Round 5
// 830.830 us; speedup vs baseline: 1.4933x; 1.0693x over previous
//
#include <hip/hip_runtime.h>
#include <float.h>

#define NQ      4096
#define NKEYS   65536
#define DKDIM   128
#define DVDIM   128
#define TOPK_N  32
#define NSPLIT  16
#define KPS     (NKEYS / NSPLIT)        // 4096 keys per split
#define BQ      64                      // queries per block (4 waves x 16)
#define NCAND   (NSPLIT * TOPK_N)       // 512 candidates per query
#define NOUT    ((size_t)NQ * TOPK_N * DKDIM)
#define KPT     32                      // keys per staged LDS tile
#define NT      (KPS / KPT)             // 128 tiles per split

typedef __attribute__((ext_vector_type(8))) short short8;   // 8 bf16
typedef __attribute__((ext_vector_type(4))) float v4f;      // MFMA acc

__device__ inline unsigned short f2bf(float f) {            // RNE fp32->bf16
    unsigned int u = __float_as_uint(f);
    return (unsigned short)((u + 0x7FFFu + ((u >> 16) & 1u)) >> 16);
}

// Cross-lane compare-exchange (within 16-lane quad; s < 16).
// Sorts descending when desc==true, ties -> lower idx first.
#define CEXX(v, id, s, desc) {                                              \
    const float _ov = __shfl_xor((v), (s));                                 \
    const int   _oi = __shfl_xor((id), (s));                                \
    const bool _first = ((v) > _ov) || ((v) == _ov && (id) < _oi);          \
    const bool _keep  = (_first == (((l16 & (s)) == 0) == (desc)));         \
    (v) = _keep ? (v) : _ov; (id) = _keep ? (id) : _oi; }

// Intra-lane compare-exchange, descending (low position keeps the larger).
#define CEXI(va, ia, vb, ib) {                                              \
    const bool _f = ((va) > (vb)) || ((va) == (vb) && (ia) < (ib));         \
    if (!_f) { const float _tv=(va); (va)=(vb); (vb)=_tv;                   \
               const int _ti=(ia); (ia)=(ib); (ib)=_ti; } }

// Compact one query's buffer (quad-orientation: lanes of a quad cooperate on
// query quad*4+r): bitonic-sort the <=32-item append region (LDS), bitonic-
// merge with the register-resident sorted pool (pv0/pv1 desc over slots l16,
// 16+l16), keep top-32 in pool.  [verified network, rounds 3-4]
__device__ __forceinline__ void sortmerge(
    float& pv0, float& pv1, int& pi0, int& pi1, const int cc,
    const float* __restrict__ bvr, const int* __restrict__ bir, const int l16)
{
    // Load append region, item index a = j*16 + l16; pad with -inf.
    float s0 = (l16      < cc) ? bvr[l16]      : -FLT_MAX;
    float s1 = (l16 + 16 < cc) ? bvr[l16 + 16] : -FLT_MAX;
    int   t0 = (l16      < cc) ? bir[l16]      : 0x7FFFFFFF;
    int   t1 = (l16 + 16 < cc) ? bir[l16 + 16] : 0x7FFFFFFF;

    // Bitonic sort-32, descending (mirrored network: desc = ((a&k)==0)).
    CEXX(s0, t0, 1, ((l16 & 2) == 0)); CEXX(s1, t1, 1, ((l16 & 2) == 0));   // k=2
    CEXX(s0, t0, 2, ((l16 & 4) == 0)); CEXX(s1, t1, 2, ((l16 & 4) == 0));   // k=4
    CEXX(s0, t0, 1, ((l16 & 4) == 0)); CEXX(s1, t1, 1, ((l16 & 4) == 0));
    CEXX(s0, t0, 4, ((l16 & 8) == 0)); CEXX(s1, t1, 4, ((l16 & 8) == 0));   // k=8
    CEXX(s0, t0, 2, ((l16 & 8) == 0)); CEXX(s1, t1, 2, ((l16 & 8) == 0));
    CEXX(s0, t0, 1, ((l16 & 8) == 0)); CEXX(s1, t1, 1, ((l16 & 8) == 0));
    CEXX(s0, t0, 8, true);  CEXX(s1, t1, 8, false);                         // k=16
    CEXX(s0, t0, 4, true);  CEXX(s1, t1, 4, false);
    CEXX(s0, t0, 2, true);  CEXX(s1, t1, 2, false);
    CEXX(s0, t0, 1, true);  CEXX(s1, t1, 1, false);
    CEXI(s0, t0, s1, t1);                                                   // k=32, s=16
    CEXX(s0, t0, 8, true);  CEXX(s1, t1, 8, true);
    CEXX(s0, t0, 4, true);  CEXX(s1, t1, 4, true);
    CEXX(s0, t0, 2, true);  CEXX(s1, t1, 2, true);
    CEXX(s0, t0, 1, true);  CEXX(s1, t1, 1, true);

    // Reverse appended (desc -> asc) to form a bitonic 64-sequence with pool.
    float c0 = __shfl_xor(s1, 15); int d0 = __shfl_xor(t1, 15);
    float c1 = __shfl_xor(s0, 15); int d1 = __shfl_xor(t0, 15);

    // Descending bitonic clean of 64 = {pv0(i=l16), pv1(16+l16), c0(32+l16),
    // c1(48+l16)}; after s=32..1 the top half (pv0,pv1) is the sorted top-32.
    CEXI(pv0, pi0, c0, d0);            // s=32
    CEXI(pv1, pi1, c1, d1);
    CEXI(pv0, pi0, pv1, pi1);          // s=16
    CEXI(c0, d0, c1, d1);
    CEXX(pv0, pi0, 8, true); CEXX(pv1, pi1, 8, true);
    CEXX(c0, d0, 8, true);   CEXX(c1, d1, 8, true);
    CEXX(pv0, pi0, 4, true); CEXX(pv1, pi1, 4, true);
    CEXX(c0, d0, 4, true);   CEXX(c1, d1, 4, true);
    CEXX(pv0, pi0, 2, true); CEXX(pv1, pi1, 2, true);
    CEXX(c0, d0, 2, true);   CEXX(c1, d1, 2, true);
    CEXX(pv0, pi0, 1, true); CEXX(pv1, pi1, 1, true);
    CEXX(c0, d0, 1, true);   CEXX(c1, d1, 1, true);
}

// ---------------------------------------------------------------------------
// Kernel A: convert q and keys to bf16 (workspace).
// ---------------------------------------------------------------------------
__global__ __launch_bounds__(256) void convert_kernel(
    const float* __restrict__ q, const float* __restrict__ keys,
    unsigned short* __restrict__ qbf, unsigned short* __restrict__ kbf)
{
    const size_t QG = (size_t)NQ * DKDIM / 8;       // 65536 groups of 8
    const size_t KG = (size_t)NKEYS * DKDIM / 8;    // 1048576
    const size_t g  = (size_t)blockIdx.x * 256 + threadIdx.x;
    if (g >= QG + KG) return;
    const float* src;
    unsigned short* dst;
    if (g < QG) { src = q + g * 8;         dst = qbf + g * 8; }
    else        { const size_t h = g - QG; src = keys + h * 8; dst = kbf + h * 8; }
    const float4 a = ((const float4*)src)[0];
    const float4 b = ((const float4*)src)[1];
    short8 o;
    o[0] = (short)f2bf(a.x); o[1] = (short)f2bf(a.y);
    o[2] = (short)f2bf(a.z); o[3] = (short)f2bf(a.w);
    o[4] = (short)f2bf(b.x); o[5] = (short)f2bf(b.y);
    o[6] = (short)f2bf(b.z); o[7] = (short)f2bf(b.w);
    *(short8*)dst = o;
}

// ---------------------------------------------------------------------------
// Kernel B: transposed-MFMA bf16 approx scores + per-(query,split) exact
// top-32 via append-buffer + periodic bitonic sort-merge.
// NEW (round 5): K tiles are LDS-staged ONCE PER BLOCK (was: each of the 4
// waves streamed the same 1 MB split from L2 independently).  2-phase
// double buffer, async-STAGE split (issue global loads for tile t+1 at loop
// top, compute tile t from LDS, ds_write stage, one barrier per 32 keys).
// LDS layout is chunk-XOR-swizzled (j ^= row&7 on 16B chunks) so the
// per-key-row ds_read_b128 is ~2-way bank-conflict (free) instead of 16-way.
// MFMA 16x16x32 with A=K-tile, B=Q-tile -> D is S^T:
//   lane l, reg r -> S[key n0 + (l>>4)*4 + r][query q0 + (l&15)].
// Selection/compaction machinery identical to round 4 (verified).
// ---------------------------------------------------------------------------
__global__ __launch_bounds__(256, 4) void score_select_kernel(
    const unsigned short* __restrict__ qbf, const unsigned short* __restrict__ kbf,
    int* __restrict__ cand)
{
    __shared__ unsigned short kst[2][KPT * DKDIM];   // 2 x 8 KB staged K tiles
    __shared__ float bv[BQ][33];    // padded append buffers (row = query)
    __shared__ int   bi[BQ][33];

    const int tid  = threadIdx.x;
    const int wave = tid >> 6;
    const int lane = tid & 63;
    const int l16  = lane & 15;
    const int quad = lane >> 4;

    // XCD-aware remap (bijective): lin = 512*a + 8*b + c  ->  split = 2c + a,
    // qgrp = b.  Blocks with lin%8 == c all land on XCD c and touch only
    // splits {2c, 2c+1}.
    const int lin   = blockIdx.y * gridDim.x + blockIdx.x;   // [0, 1024)
    const int split = ((lin & 7) << 1) | (lin >> 9);
    const int qgrp  = (lin >> 3) & 63;
    const int q0    = qgrp * BQ + wave * 16;
    const int nbase = split * KPS;

    float* __restrict__ bvq = &bv[wave * 16 + l16][0];   // this lane's query row
    int*   __restrict__ biq = &bi[wave * 16 + l16][0];

    // Q fragments (B-operand), resident for the whole kernel
    // (lane holds Q[q0+l16][quad*8 + 32t + j]).
    short8 afrag[4];
#pragma unroll
    for (int t = 0; t < 4; ++t)
        afrag[t] = *(const short8*)(qbf + (size_t)(q0 + l16) * DKDIM + t * 32 + quad * 8);

    // Register pool in quad-orientation (query quad*4+r; sorted desc over
    // slots l16, 16+l16).  vmq/cnt in lane-orientation (query l16).
    float pv0[4], pv1[4];
    int   pi0[4], pi1[4];
#pragma unroll
    for (int r = 0; r < 4; ++r) { pv0[r] = pv1[r] = -FLT_MAX; pi0[r] = pi1[r] = 0; }
    float vmq = -FLT_MAX;
    int   cnt = 0;

    auto select16 = [&](const v4f acc, const int n0) {
        // Per-lane hits: 4 keys (n0 + quad*4 + r) of query l16.
        const int h0 = acc[0] > vmq;
        const int h1 = acc[1] > vmq;
        const int h2 = acc[2] > vmq;
        const int h3 = acc[3] > vmq;
        const int nh = h0 + h1 + h2 + h3;
        // Cross-quad (stride-16/32) sum + prefix for this query column.
        const int s16   = __shfl_xor(nh, 16);
        const int psum  = nh + s16;
        const int sx32  = __shfl_xor(psum, 32);
        const int nhcol = psum + sx32;
        if (__ballot(cnt + nhcol > 32)) {            // wave-uniform compaction
#pragma unroll
            for (int r = 0; r < 4; ++r) {
                const int cc = __shfl(cnt, quad * 4 + r);
                const int qq = wave * 16 + quad * 4 + r;
                sortmerge(pv0[r], pv1[r], pi0[r], pi1[r], cc, &bv[qq][0], &bi[qq][0], l16);
            }
            // Redistribute pool-min (slot 31 = pv1 at l16==15 of owner quad)
            // from quad-orientation to lane-orientation (query l16).
            const float t0v = __shfl(pv1[0], (l16 >> 2) * 16 + 15);
            const float t1v = __shfl(pv1[1], (l16 >> 2) * 16 + 15);
            const float t2v = __shfl(pv1[2], (l16 >> 2) * 16 + 15);
            const float t3v = __shfl(pv1[3], (l16 >> 2) * 16 + 15);
            const float a01 = (l16 & 1) ? t1v : t0v;
            const float a23 = (l16 & 1) ? t3v : t2v;
            vmq = (l16 & 2) ? a23 : a01;
            cnt = 0;
        }
        // Parallel append (old-vm hits; superset of true top-32 is safe).
        int pos = cnt + ((quad & 1) ? s16 : 0) + ((quad & 2) ? sx32 : 0);
        if (h0) { bvq[pos] = acc[0]; biq[pos] = n0 + quad * 4;     ++pos; }
        if (h1) { bvq[pos] = acc[1]; biq[pos] = n0 + quad * 4 + 1; ++pos; }
        if (h2) { bvq[pos] = acc[2]; biq[pos] = n0 + quad * 4 + 2; ++pos; }
        if (h3) { bvq[pos] = acc[3]; biq[pos] = n0 + quad * 4 + 3; }
        cnt += nhcol;
    };

    // ---- Staging setup: thread stages 16B chunks c0, c1 of each 8 KB tile.
    // LDS dest is chunk-XOR-swizzled (involution, row-local): j' = j^(row&7).
    const unsigned short* ksrc = kbf + (size_t)nbase * DKDIM;
    const int c0 = tid, c1 = tid + 256;
    const int d0 = ((c0 >> 4) * 128) + (((c0 & 15) ^ ((c0 >> 4) & 7)) * 8);
    const int d1 = ((c1 >> 4) * 128) + (((c1 & 15) ^ ((c1 >> 4) & 7)) * 8);

    // Prologue: stage tile 0.
    {
        const short8 a = *(const short8*)(ksrc + c0 * 8);
        const short8 b = *(const short8*)(ksrc + c1 * 8);
        *(short8*)&kst[0][d0] = a;
        *(short8*)&kst[0][d1] = b;
    }
    __syncthreads();

    int cur = 0;
    const int sx = l16 & 7;
    for (int t = 0; t < NT; ++t) {
        // Issue next tile's global loads EARLY (latency hides under compute).
        short8 nA, nB;
        const bool more = (t + 1 < NT);
        if (more) {
            const unsigned short* s = ksrc + (size_t)(t + 1) * (KPT * DKDIM);
            nA = *(const short8*)(s + c0 * 8);
            nB = *(const short8*)(s + c1 * 8);
        }
        // Two 16-key passes from kst[cur] (swizzled ds_read_b128).
#pragma unroll
        for (int j2 = 0; j2 < 2; ++j2) {
            const unsigned short* kr = &kst[cur][(j2 * 16 + l16) * 128];
            v4f acc = {0.f, 0.f, 0.f, 0.f};
#pragma unroll
            for (int tt = 0; tt < 4; ++tt) {
                const short8 bfrag = *(const short8*)(kr + ((quad + tt * 4) ^ sx) * 8);
                acc = __builtin_amdgcn_mfma_f32_16x16x32_bf16(bfrag, afrag[tt], acc, 0, 0, 0);
            }
            select16(acc, nbase + t * KPT + j2 * 16);
        }
        // Write the staged tile, then one barrier per 32 keys.
        if (more) {
            *(short8*)&kst[cur ^ 1][d0] = nA;
            *(short8*)&kst[cur ^ 1][d1] = nB;
        }
        __syncthreads();
        cur ^= 1;
    }

    // Final flush + writeout (quad-orientation; pool sorted desc).
#pragma unroll
    for (int r = 0; r < 4; ++r) {
        const int cc = __shfl(cnt, quad * 4 + r);
        const int qq = wave * 16 + quad * 4 + r;
        sortmerge(pv0[r], pv1[r], pi0[r], pi1[r], cc, &bv[qq][0], &bi[qq][0], l16);
        const size_t base = ((size_t)(q0 + quad * 4 + r) * NSPLIT + split) * TOPK_N;
        cand[base + l16]      = pi0[r];
        cand[base + 16 + l16] = pi1[r];
    }
}

// ---------------------------------------------------------------------------
// Kernel C: exact fp32 rescore of 512 candidates (sequential fmaf chain,
// bitwise-matches reference), bitonic sort (desc, tie -> lower idx), gather.
// One block (512 threads) per query.
// ---------------------------------------------------------------------------
__global__ __launch_bounds__(512) void rescore_gather_kernel(
    const float* __restrict__ qg, const float* __restrict__ keys,
    const float* __restrict__ values, const int* __restrict__ cand,
    float* __restrict__ out)
{
    __shared__ float qrow[DKDIM];
    __shared__ float ss[NCAND];
    __shared__ int   si[NCAND];
    const int bt  = blockIdx.x;
    const int tid = threadIdx.x;

    if (tid < DKDIM) qrow[tid] = qg[(size_t)bt * DKDIM + tid];
    __syncthreads();

    const int idx = cand[(size_t)bt * NCAND + tid];
    const float4* krow = (const float4*)(keys + (size_t)idx * DKDIM);
    float s = 0.f;
#pragma unroll
    for (int d4 = 0; d4 < DKDIM / 4; ++d4) {
        const float4 k4 = krow[d4];
        const float4 q4 = *(const float4*)&qrow[4 * d4];
        s = fmaf(q4.x, k4.x, s);
        s = fmaf(q4.y, k4.y, s);
        s = fmaf(q4.z, k4.z, s);
        s = fmaf(q4.w, k4.w, s);
    }
    ss[tid] = s; si[tid] = idx;
    __syncthreads();

    for (int k = 2; k <= NCAND; k <<= 1) {
        for (int j = k >> 1; j > 0; j >>= 1) {
            const int ixj = tid ^ j;
            if (ixj > tid) {
                const bool dirDesc = ((tid & k) == 0);
                const float sa = ss[tid], sb = ss[ixj];
                const int   ia = si[tid], ib = si[ixj];
                const bool before = (sa > sb) || (sa == sb && ia < ib);
                if (before != dirDesc) {
                    ss[tid] = sb; ss[ixj] = sa;
                    si[tid] = ib; si[ixj] = ia;
                }
            }
            __syncthreads();
        }
    }

    const int lane = tid & 31;
    const int rb   = tid >> 5;          // [0, 16)
#pragma unroll
    for (int r = 0; r < 2; ++r) {
        const int row = rb + 16 * r;
        const int n   = si[row];
        const float4 kv = *(const float4*)(keys   + (size_t)n * DKDIM + 4 * lane);
        const float4 vv = *(const float4*)(values + (size_t)n * DVDIM + 4 * lane);
        const size_t ob = ((size_t)bt * TOPK_N + row) * DKDIM + 4 * lane;
        *(float4*)(out + ob)        = kv;
        *(float4*)(out + NOUT + ob) = vv;
    }
}

extern "C" void kernel_launch(void* const* d_in, const int* in_sizes, int n_in,
                              void* d_out, int out_size, void* d_ws, size_t ws_size,
                              hipStream_t stream)
{
    const float* q      = (const float*)d_in[0];
    const float* keys   = (const float*)d_in[1];
    const float* values = (const float*)d_in[2];
    float* out = (float*)d_out;

    unsigned short* qbf = (unsigned short*)d_ws;                               // 1 MB
    unsigned short* kbf = (unsigned short*)((char*)d_ws + (1u << 20));         // 16 MB
    int* cand = (int*)((char*)d_ws + (17u << 20));                             // 8 MB

    const int cvt_groups = (NQ + NKEYS) * DKDIM / 8;
    convert_kernel<<<(cvt_groups + 255) / 256, 256, 0, stream>>>(q, keys, qbf, kbf);
    score_select_kernel<<<dim3(NQ / BQ, NSPLIT), 256, 0, stream>>>(qbf, kbf, cand);
    rescore_gather_kernel<<<NQ, 512, 0, stream>>>(q, keys, values, cand, out);
}

// Round 6
// 602.254 us; speedup vs baseline: 2.0601x; 1.3795x over previous
//
#include <hip/hip_runtime.h>
#include <float.h>

#define NQ      4096
#define NKEYS   65536
#define DKDIM   128
#define DVDIM   128
#define TOPK_N  32
#define NSPLIT  16
#define KPS     (NKEYS / NSPLIT)        // 4096 keys per split (li fits 12 bits)
#define BQ      64                      // queries per block (4 waves x 16)
#define NCAND   (NSPLIT * TOPK_N)       // 512 candidates per query
#define NARROW  128                     // exact-rescore width in kernel C
#define NOUT    ((size_t)NQ * TOPK_N * DKDIM)
#define KPT     32                      // keys per staged LDS tile
#define NT      (KPS / KPT)             // 128 tiles per split

typedef __attribute__((ext_vector_type(8))) short short8;   // 8 bf16
typedef __attribute__((ext_vector_type(4))) float v4f;      // MFMA acc

__device__ inline unsigned short f2bf(float f) {            // RNE fp32->bf16
    unsigned int u = __float_as_uint(f);
    return (unsigned short)((u + 0x7FFFu + ((u >> 16) & 1u)) >> 16);
}

// Packed candidate: (monotone-folded fp32 score, top 20 bits) | (4095 - li).
// Unsigned-descending order == (score desc, tie -> lower li).  0 == empty pad
// (any real score folds to >= 0x00800000).
__device__ inline unsigned packpk(float s, unsigned li) {
    unsigned u = __float_as_uint(s);
    u = ((int)u < 0) ? ~u : (u | 0x80000000u);
    return (u & 0xFFFFF000u) | (4095u - li);
}
// Lower bound of the score encoded in pk (truncation rounds toward -inf).
__device__ inline float unpack_lb(unsigned pk) {
    const unsigned m = pk & 0xFFFFF000u;
    const unsigned b = (m & 0x80000000u) ? (m & 0x7FFFFFFFu) : ~m;
    return __uint_as_float(b);
}

// Cross-lane compare-exchange on one packed word (within 16-lane quad; s<16).
#define CEXU(p, s, desc) {                                                  \
    const unsigned _o = (unsigned)__shfl_xor((int)(p), (s));                \
    const bool _first = (p) > _o;                                           \
    const bool _keep  = (_first == (((l16 & (s)) == 0) == (desc)));         \
    (p) = _keep ? (p) : _o; }
// Intra-lane: keep larger in a (descending position).
#define CEXUI(pa, pb) { if ((pb) > (pa)) { const unsigned _t=(pa); (pa)=(pb); (pb)=_t; } }

// Compact one query's append region (<=32 packed words in LDS) into the
// register-resident sorted pool (p0/p1 desc over slots l16, 16+l16).
// Bitonic sort-32 + first merge stage + p-side cleanup only (the c-side is
// discarded after the bitonic split fixes the top-32 set).
__device__ __forceinline__ void sortmergeU(
    unsigned& p0, unsigned& p1, const int cc,
    const unsigned* __restrict__ bqr, const int l16)
{
    unsigned s0 = (l16      < cc) ? bqr[l16]      : 0u;
    unsigned s1 = (l16 + 16 < cc) ? bqr[l16 + 16] : 0u;

    // Bitonic sort-32, descending (mirrored: desc = ((a&k)==0)).
    CEXU(s0, 1, ((l16 & 2) == 0)); CEXU(s1, 1, ((l16 & 2) == 0));   // k=2
    CEXU(s0, 2, ((l16 & 4) == 0)); CEXU(s1, 2, ((l16 & 4) == 0));   // k=4
    CEXU(s0, 1, ((l16 & 4) == 0)); CEXU(s1, 1, ((l16 & 4) == 0));
    CEXU(s0, 4, ((l16 & 8) == 0)); CEXU(s1, 4, ((l16 & 8) == 0));   // k=8
    CEXU(s0, 2, ((l16 & 8) == 0)); CEXU(s1, 2, ((l16 & 8) == 0));
    CEXU(s0, 1, ((l16 & 8) == 0)); CEXU(s1, 1, ((l16 & 8) == 0));
    CEXU(s0, 8, true);  CEXU(s1, 8, false);                         // k=16
    CEXU(s0, 4, true);  CEXU(s1, 4, false);
    CEXU(s0, 2, true);  CEXU(s1, 2, false);
    CEXU(s0, 1, true);  CEXU(s1, 1, false);
    CEXUI(s0, s1);                                                  // k=32 s=16
    CEXU(s0, 8, true);  CEXU(s1, 8, true);
    CEXU(s0, 4, true);  CEXU(s1, 4, true);
    CEXU(s0, 2, true);  CEXU(s1, 2, true);
    CEXU(s0, 1, true);  CEXU(s1, 1, true);

    // Reverse (desc -> asc): bitonic 64-seq {p0,p1,c0,c1}.
    unsigned c0 = (unsigned)__shfl_xor((int)s1, 15);
    unsigned c1 = (unsigned)__shfl_xor((int)s0, 15);

    // s=32: bitonic split -- after this, {p0,p1} hold the top-32 set.
    CEXUI(p0, c0);
    CEXUI(p1, c1);
    // p-side cleanup only (c-side discarded).
    CEXUI(p0, p1);                     // s=16
    CEXU(p0, 8, true); CEXU(p1, 8, true);
    CEXU(p0, 4, true); CEXU(p1, 4, true);
    CEXU(p0, 2, true); CEXU(p1, 2, true);
    CEXU(p0, 1, true); CEXU(p1, 1, true);
}

// ---------------------------------------------------------------------------
// Kernel A: convert q and keys to bf16 (workspace).
// ---------------------------------------------------------------------------
__global__ __launch_bounds__(256) void convert_kernel(
    const float* __restrict__ q, const float* __restrict__ keys,
    unsigned short* __restrict__ qbf, unsigned short* __restrict__ kbf)
{
    const size_t QG = (size_t)NQ * DKDIM / 8;       // 65536 groups of 8
    const size_t KG = (size_t)NKEYS * DKDIM / 8;    // 1048576
    const size_t g  = (size_t)blockIdx.x * 256 + threadIdx.x;
    if (g >= QG + KG) return;
    const float* src;
    unsigned short* dst;
    if (g < QG) { src = q + g * 8;         dst = qbf + g * 8; }
    else        { const size_t h = g - QG; src = keys + h * 8; dst = kbf + h * 8; }
    const float4 a = ((const float4*)src)[0];
    const float4 b = ((const float4*)src)[1];
    short8 o;
    o[0] = (short)f2bf(a.x); o[1] = (short)f2bf(a.y);
    o[2] = (short)f2bf(a.z); o[3] = (short)f2bf(a.w);
    o[4] = (short)f2bf(b.x); o[5] = (short)f2bf(b.y);
    o[6] = (short)f2bf(b.z); o[7] = (short)f2bf(b.w);
    *(short8*)dst = o;
}

// ---------------------------------------------------------------------------
// Kernel B: transposed-MFMA bf16 approx scores + per-(query,split) top-32 as
// PACKED 32-bit candidates (score-top20 | 4095-li).  LDS-staged K tiles
// (double-buffered, async-split staging), one selection pass per 32 keys.
// LDS 24.8 KB -> 6 blocks/CU (24 waves/CU).
// MFMA 16x16x32 with A=K-tile, B=Q-tile -> D is S^T:
//   lane l, reg r -> S[key n0 + (l>>4)*4 + r][query q0 + (l&15)].
// Selection: lane owns query l16; vmf = lower-bound decode of pool-min
// (stale between compactions -> superset, safe); hits append packed words at
// ballot-prefix positions; wave-uniform compaction via sortmergeU.
// ---------------------------------------------------------------------------
__global__ __launch_bounds__(256, 6) void score_select_kernel(
    const unsigned short* __restrict__ qbf, const unsigned short* __restrict__ kbf,
    unsigned* __restrict__ cand)
{
    __shared__ unsigned short kst[2][KPT * DKDIM];   // 2 x 8 KB staged K tiles
    __shared__ unsigned bq[BQ][33];                  // 8.25 KB packed appends

    const int tid  = threadIdx.x;
    const int wave = tid >> 6;
    const int lane = tid & 63;
    const int l16  = lane & 15;
    const int quad = lane >> 4;

    // XCD-aware remap (bijective): lin = 512*a + 8*b + c -> split = 2c + a,
    // qgrp = b.  Blocks with lin%8 == c land on XCD c; touch splits {2c,2c+1}.
    const int lin   = blockIdx.y * gridDim.x + blockIdx.x;   // [0, 1024)
    const int split = ((lin & 7) << 1) | (lin >> 9);
    const int qgrp  = (lin >> 3) & 63;
    const int q0    = qgrp * BQ + wave * 16;
    const int nbase = split * KPS;

    unsigned* __restrict__ bqr = &bq[wave * 16 + l16][0];   // lane's query row

    // Q fragments (B-operand): lane holds Q[q0+l16][quad*8 + 32t + j].
    short8 afrag[4];
#pragma unroll
    for (int t = 0; t < 4; ++t)
        afrag[t] = *(const short8*)(qbf + (size_t)(q0 + l16) * DKDIM + t * 32 + quad * 8);

    // Pool (quad-orientation: query quad*4+r, sorted desc over l16, 16+l16).
    unsigned pk0[4], pk1[4];
#pragma unroll
    for (int r = 0; r < 4; ++r) { pk0[r] = 0u; pk1[r] = 0u; }
    float vmf = -FLT_MAX;     // lane-orientation threshold (query l16)
    int   cnt = 0;

    auto select32 = [&](const v4f a1, const v4f a2, const int n0loc) {
        // 8 scores of query l16: keys n0loc + quad*4 + r (+16).
        const int h0 = a1[0] > vmf, h1 = a1[1] > vmf, h2 = a1[2] > vmf, h3 = a1[3] > vmf;
        const int h4 = a2[0] > vmf, h5 = a2[1] > vmf, h6 = a2[2] > vmf, h7 = a2[3] > vmf;
        const int nh = h0 + h1 + h2 + h3 + h4 + h5 + h6 + h7;
        const int s16   = __shfl_xor(nh, 16);
        const int psum  = nh + s16;
        const int sx32  = __shfl_xor(psum, 32);
        const int nhcol = psum + sx32;
        if (__ballot(cnt + nhcol > 32)) {            // wave-uniform compaction
#pragma unroll
            for (int r = 0; r < 4; ++r) {
                const int cc = __shfl(cnt, quad * 4 + r);
                sortmergeU(pk0[r], pk1[r], cc, &bq[wave * 16 + quad * 4 + r][0], l16);
            }
            // Pool-min (slot 31 = pk1 at l16==15 of owner quad) -> lane-orient.
            const unsigned t0 = (unsigned)__shfl((int)pk1[0], (l16 >> 2) * 16 + 15);
            const unsigned t1 = (unsigned)__shfl((int)pk1[1], (l16 >> 2) * 16 + 15);
            const unsigned t2 = (unsigned)__shfl((int)pk1[2], (l16 >> 2) * 16 + 15);
            const unsigned t3 = (unsigned)__shfl((int)pk1[3], (l16 >> 2) * 16 + 15);
            const unsigned a01 = (l16 & 1) ? t1 : t0;
            const unsigned a23 = (l16 & 1) ? t3 : t2;
            vmf = unpack_lb((l16 & 2) ? a23 : a01);
            cnt = 0;
        }
        int pos = cnt + ((quad & 1) ? s16 : 0) + ((quad & 2) ? sx32 : 0);
        const unsigned lb = (unsigned)(n0loc + quad * 4);
        if (h0) { bqr[pos] = packpk(a1[0], lb);      ++pos; }
        if (h1) { bqr[pos] = packpk(a1[1], lb + 1);  ++pos; }
        if (h2) { bqr[pos] = packpk(a1[2], lb + 2);  ++pos; }
        if (h3) { bqr[pos] = packpk(a1[3], lb + 3);  ++pos; }
        if (h4) { bqr[pos] = packpk(a2[0], lb + 16); ++pos; }
        if (h5) { bqr[pos] = packpk(a2[1], lb + 17); ++pos; }
        if (h6) { bqr[pos] = packpk(a2[2], lb + 18); ++pos; }
        if (h7) { bqr[pos] = packpk(a2[3], lb + 19); }
        cnt += nhcol;
    };

    // ---- Staging: thread stages 16B chunks c0, c1; chunk-XOR swizzle.
    const unsigned short* ksrc = kbf + (size_t)nbase * DKDIM;
    const int c0 = tid, c1 = tid + 256;
    const int d0 = ((c0 >> 4) * 128) + (((c0 & 15) ^ ((c0 >> 4) & 7)) * 8);
    const int d1 = ((c1 >> 4) * 128) + (((c1 & 15) ^ ((c1 >> 4) & 7)) * 8);

    {   // Prologue: stage tile 0.
        const short8 a = *(const short8*)(ksrc + c0 * 8);
        const short8 b = *(const short8*)(ksrc + c1 * 8);
        *(short8*)&kst[0][d0] = a;
        *(short8*)&kst[0][d1] = b;
    }
    __syncthreads();

    int cur = 0;
    const int sx = l16 & 7;
    for (int t = 0; t < NT; ++t) {
        short8 nA, nB;
        const bool more = (t + 1 < NT);
        if (more) {   // issue next tile's loads early
            const unsigned short* s = ksrc + (size_t)(t + 1) * (KPT * DKDIM);
            nA = *(const short8*)(s + c0 * 8);
            nB = *(const short8*)(s + c1 * 8);
        }
        // Two independent MFMA chains over the 32-key tile, then ONE select.
        const unsigned short* kr0 = &kst[cur][(l16) * 128];
        const unsigned short* kr1 = &kst[cur][(16 + l16) * 128];
        v4f acc1 = {0.f, 0.f, 0.f, 0.f};
        v4f acc2 = {0.f, 0.f, 0.f, 0.f};
#pragma unroll
        for (int tt = 0; tt < 4; ++tt) {
            const short8 b0 = *(const short8*)(kr0 + ((quad + tt * 4) ^ sx) * 8);
            const short8 b1 = *(const short8*)(kr1 + ((quad + tt * 4) ^ sx) * 8);
            acc1 = __builtin_amdgcn_mfma_f32_16x16x32_bf16(b0, afrag[tt], acc1, 0, 0, 0);
            acc2 = __builtin_amdgcn_mfma_f32_16x16x32_bf16(b1, afrag[tt], acc2, 0, 0, 0);
        }
        select32(acc1, acc2, t * KPT);
        if (more) {
            *(short8*)&kst[cur ^ 1][d0] = nA;
            *(short8*)&kst[cur ^ 1][d1] = nB;
        }
        __syncthreads();
        cur ^= 1;
    }

    // Final flush + writeout (quad-orientation; pool sorted desc).
#pragma unroll
    for (int r = 0; r < 4; ++r) {
        const int cc = __shfl(cnt, quad * 4 + r);
        sortmergeU(pk0[r], pk1[r], cc, &bq[wave * 16 + quad * 4 + r][0], l16);
        const size_t base = ((size_t)(q0 + quad * 4 + r) * NSPLIT + split) * TOPK_N;
        cand[base + l16]      = pk0[r];
        cand[base + 16 + l16] = pk1[r];
    }
}

// ---------------------------------------------------------------------------
// Kernel C: narrow-then-rescore.  Sort 512 packed candidates (uint desc,
// cheap), fp32-rescore the top NARROW=128 exactly (sequential fmaf chain),
// exact bitonic sort of 128 (desc, tie -> lower idx), gather top-32.
// Safety: global-top-32 approx scores clear the 128th-boundary by ~4.0 vs
// ~0.3 bf16+trunc error.  One block (512 threads) per query.
// ---------------------------------------------------------------------------
__global__ __launch_bounds__(512) void rescore_gather_kernel(
    const float* __restrict__ qg, const float* __restrict__ keys,
    const float* __restrict__ values, const unsigned* __restrict__ cand,
    float* __restrict__ out)
{
    __shared__ float    qrow[DKDIM];
    __shared__ unsigned spk[NCAND];
    __shared__ int      sn[NCAND];
    __shared__ float    ss[NARROW];
    __shared__ int      si[NARROW];
    const int bt  = blockIdx.x;
    const int tid = threadIdx.x;

    if (tid < DKDIM) qrow[tid] = qg[(size_t)bt * DKDIM + tid];
    {
        const unsigned pk = cand[(size_t)bt * NCAND + tid];
        spk[tid] = pk;
        sn[tid]  = (tid >> 5) * KPS + (int)(4095u - (pk & 0xFFFu));
    }
    __syncthreads();

    // Bitonic sort-512 desc by packed word (tie -> lower global idx).
    for (int k = 2; k <= NCAND; k <<= 1) {
        for (int j = k >> 1; j > 0; j >>= 1) {
            const int ixj = tid ^ j;
            if (ixj > tid) {
                const bool dirDesc = ((tid & k) == 0);
                const unsigned pa = spk[tid], pb = spk[ixj];
                const int      na = sn[tid],  nb = sn[ixj];
                const bool before = (pa > pb) || (pa == pb && na < nb);
                if (before != dirDesc) {
                    spk[tid] = pb; spk[ixj] = pa;
                    sn[tid]  = nb; sn[ixj]  = na;
                }
            }
            __syncthreads();
        }
    }

    // Exact fp32 rescore of the top NARROW (sequential fmaf chain).
    if (tid < NARROW) {
        const int n = sn[tid];
        const float4* krow = (const float4*)(keys + (size_t)n * DKDIM);
        float s = 0.f;
#pragma unroll
        for (int d4 = 0; d4 < DKDIM / 4; ++d4) {
            const float4 k4 = krow[d4];
            const float4 q4 = *(const float4*)&qrow[4 * d4];
            s = fmaf(q4.x, k4.x, s);
            s = fmaf(q4.y, k4.y, s);
            s = fmaf(q4.z, k4.z, s);
            s = fmaf(q4.w, k4.w, s);
        }
        ss[tid] = s; si[tid] = n;
    }
    __syncthreads();

    // Exact bitonic sort-128 (desc, tie -> lower idx).
    for (int k = 2; k <= NARROW; k <<= 1) {
        for (int j = k >> 1; j > 0; j >>= 1) {
            const int ixj = tid ^ j;
            if (tid < NARROW && ixj > tid) {
                const bool dirDesc = ((tid & k) == 0);
                const float sa = ss[tid], sb = ss[ixj];
                const int   ia = si[tid], ib = si[ixj];
                const bool before = (sa > sb) || (sa == sb && ia < ib);
                if (before != dirDesc) {
                    ss[tid] = sb; ss[ixj] = sa;
                    si[tid] = ib; si[ixj] = ia;
                }
            }
            __syncthreads();
        }
    }

    // Gather top-32 K and V rows.
    const int lane = tid & 31;
    const int rb   = tid >> 5;          // [0, 16)
#pragma unroll
    for (int r = 0; r < 2; ++r) {
        const int row = rb + 16 * r;
        const int n   = si[row];
        const float4 kv = *(const float4*)(keys   + (size_t)n * DKDIM + 4 * lane);
        const float4 vv = *(const float4*)(values + (size_t)n * DVDIM + 4 * lane);
        const size_t ob = ((size_t)bt * TOPK_N + row) * DKDIM + 4 * lane;
        *(float4*)(out + ob)        = kv;
        *(float4*)(out + NOUT + ob) = vv;
    }
}

extern "C" void kernel_launch(void* const* d_in, const int* in_sizes, int n_in,
                              void* d_out, int out_size, void* d_ws, size_t ws_size,
                              hipStream_t stream)
{
    const float* q      = (const float*)d_in[0];
    const float* keys   = (const float*)d_in[1];
    const float* values = (const float*)d_in[2];
    float* out = (float*)d_out;

    unsigned short* qbf = (unsigned short*)d_ws;                               // 1 MB
    unsigned short* kbf = (unsigned short*)((char*)d_ws + (1u << 20));         // 16 MB
    unsigned* cand = (unsigned*)((char*)d_ws + (17u << 20));                   // 8 MB

    const int cvt_groups = (NQ + NKEYS) * DKDIM / 8;
    convert_kernel<<<(cvt_groups + 255) / 256, 256, 0, stream>>>(q, keys, qbf, kbf);
    score_select_kernel<<<dim3(NQ / BQ, NSPLIT), 256, 0, stream>>>(qbf, kbf, cand);
    rescore_gather_kernel<<<NQ, 512, 0, stream>>>(q, keys, values, cand, out);
}